// Round 7
// baseline (482.225 us; speedup 1.0000x reference)
//
#include <hip/hip_runtime.h>
#include <hip/hip_bf16.h>
#include <stdint.h>

// ---------------------------------------------------------------------------
// EfficientCrossAttention on MI355X (gfx950), bf16 MFMA pipeline.
// prep (cast+transpose) -> fused Q/KV projection GEMM -> flash attention
// (S^T trick, lsum-via-MFMA, bh-major grid for XCD/L2 KV locality) ->
// Oproj GEMM.
// d_ws layout:
//   WqT @0MB  WkvT @2MB  WoT @6MB  qb @8MB  kvb @24MB
//   Qp (B*H,2048,64) @40MB   Kb (B*H,2048,64) @56MB
//   Vt (B*H,64,2048) @72MB   Ob (8192x1024)   @88MB
// ---------------------------------------------------------------------------

typedef __bf16 bf16_t;
typedef __bf16 bf16x8 __attribute__((ext_vector_type(8)));
typedef __bf16 bf16x4 __attribute__((ext_vector_type(4)));
typedef short  s16x4  __attribute__((ext_vector_type(4)));
typedef float  f32x4  __attribute__((ext_vector_type(4)));

#define MFMA16x32(a, b, c) __builtin_amdgcn_mfma_f32_16x16x32_bf16((a), (b), (c), 0, 0, 0)

__device__ __forceinline__ f32x4 mfma16x16(bf16x4 a, bf16x4 b, f32x4 c) {
#if __has_builtin(__builtin_amdgcn_mfma_f32_16x16x16_bf16)
    return __builtin_amdgcn_mfma_f32_16x16x16_bf16(a, b, c, 0, 0, 0);
#else
    return __builtin_amdgcn_mfma_f32_16x16x16bf16_1k(
        __builtin_bit_cast(s16x4, a), __builtin_bit_cast(s16x4, b), c, 0, 0, 0);
#endif
}

__device__ __forceinline__ float fast_exp2(float x) {
#if __has_builtin(__builtin_amdgcn_exp2f)
    return __builtin_amdgcn_exp2f(x);
#else
    return exp2f(x);
#endif
}

// async global->LDS, 16B/lane; LDS dest = wave-uniform base + lane*16
__device__ __forceinline__ void gload16(const void* g, const void* l) {
    __builtin_amdgcn_global_load_lds(
        (__attribute__((address_space(1))) void*)(uintptr_t)g,
        (__attribute__((address_space(3))) void*)(uintptr_t)l,
        16, 0, 0);
}

// log2(e)/sqrt(HD=64), folded into the Q projection epilogue
#define ATTN_SCALE 0.18033688011112042f

// ---------------------------------------------------------------------------
// merged prep: fp32->bf16 casts (blocks 0..8191) + 3 weight transposes
__global__ void prep_kernel(const float* __restrict__ q, const float* __restrict__ kv,
                            const float* __restrict__ Wq, const float* __restrict__ Wkv,
                            const float* __restrict__ Wo, bf16_t* __restrict__ qb,
                            bf16_t* __restrict__ kvb, bf16_t* __restrict__ WqT,
                            bf16_t* __restrict__ WkvT, bf16_t* __restrict__ WoT) {
    __shared__ float tile[64][65];
    int bid = blockIdx.x;
    const int t = threadIdx.x;
    if (bid < 8192) {
        const float* in;
        bf16_t* out;
        if (bid < 4096) { in = q; out = qb; }
        else            { in = kv; out = kvb; bid -= 4096; }
        int i = (bid * 256 + t) * 8;
        const float4* p = (const float4*)(in + i);
        float4 x = p[0], y = p[1];
        bf16x8 v;
        v[0] = (bf16_t)x.x; v[1] = (bf16_t)x.y; v[2] = (bf16_t)x.z; v[3] = (bf16_t)x.w;
        v[4] = (bf16_t)y.x; v[5] = (bf16_t)y.y; v[6] = (bf16_t)y.z; v[7] = (bf16_t)y.w;
        *(bf16x8*)(out + i) = v;
        return;
    }
    bid -= 8192;
    int z = bid >> 9, rem = bid & 511;
    int xb = rem & 31, yb = rem >> 5;
    const float* W;
    bf16_t* WT;
    int N;
    if (z == 0)      { W = Wq;  WT = WqT;  N = 1024; }
    else if (z == 1) { W = Wkv; WT = WkvT; N = 2048; }
    else             { W = Wo;  WT = WoT;  N = 1024; }
    if (xb * 64 >= N) return;
    const int K = 1024;
    const int n0 = xb * 64, k0 = yb * 64;
#pragma unroll
    for (int i = 0; i < 16; ++i) {
        int idx = i * 256 + t;
        int r = idx >> 6, c = idx & 63;
        tile[r][c] = W[(size_t)(k0 + r) * N + n0 + c];
    }
    __syncthreads();
#pragma unroll
    for (int i = 0; i < 16; ++i) {
        int idx = i * 256 + t;
        int r = idx >> 6, c = idx & 63;
        WT[(size_t)(n0 + r) * K + k0 + c] = (bf16_t)tile[c][r];
    }
}

// ---------------------------------------------------------------------------
// Fused Q + KV projection GEMM (one launch, 24x64 = 1536 blocks).
// blockIdx.x < 8: Qproj (scaled, -> Qp); else KVproj (-> Kb / Vt).
// 128x128 tiles, m97 staging, 2-bit XOR chunk swizzle.
__global__ __launch_bounds__(256, 3)
void gemm_qkv(const bf16_t* __restrict__ qb, const bf16_t* __restrict__ kvb,
              const bf16_t* __restrict__ WqT, const bf16_t* __restrict__ WkvT,
              const float* __restrict__ bq, const float* __restrict__ bkv,
              bf16_t* __restrict__ Qp, bf16_t* __restrict__ Kb,
              bf16_t* __restrict__ Vt) {
    __shared__ __align__(16) char pool[16384 + 4 * 64 * 72 * 2];
    bf16_t* sA = (bf16_t*)pool;
    bf16_t* sB = (bf16_t*)(pool + 8192);

    const int tid  = threadIdx.x;
    const int lane = tid & 63, w = tid >> 6;
    const int wr = w >> 1, wc = w & 1;
    const int quad = lane >> 4, l15 = lane & 15;
    const int x3 = l15 & 3;
    const bool isQ = blockIdx.x < 8;
    const bf16_t* A    = isQ ? qb : kvb;
    const bf16_t* BT   = isQ ? WqT : WkvT;
    const float*  bias = isQ ? bq : bkv;
    const int row0 = blockIdx.y * 128;
    const int col0 = (isQ ? blockIdx.x : (blockIdx.x - 8)) * 128;
    const int K = 1024;

    f32x4 acc[4][4];
    const f32x4 fz = {0.f, 0.f, 0.f, 0.f};
#pragma unroll
    for (int m = 0; m < 4; ++m)
#pragma unroll
        for (int n = 0; n < 4; ++n) acc[m][n] = fz;

    for (int kt = 0; kt < K; kt += 32) {
#pragma unroll
        for (int i = 0; i < 2; ++i) {
            int c = i * 256 + tid;
            int r = c >> 2, cr = c & 3;
            int g = cr ^ (r & 3);
            gload16(A + (size_t)(row0 + r) * K + kt + g * 8,
                    (const char*)sA + i * 4096 + w * 1024);
            gload16(BT + (size_t)(col0 + r) * K + kt + g * 8,
                    (const char*)sB + i * 4096 + w * 1024);
        }
        __syncthreads();

        bf16x8 af[4], bfr[4];
#pragma unroll
        for (int m = 0; m < 4; ++m)
            af[m] = *(const bf16x8*)(sA + (wr * 64 + m * 16 + l15) * 32 + (quad ^ x3) * 8);
#pragma unroll
        for (int n = 0; n < 4; ++n)
            bfr[n] = *(const bf16x8*)(sB + (wc * 64 + n * 16 + l15) * 32 + (quad ^ x3) * 8);
#pragma unroll
        for (int m = 0; m < 4; ++m)
#pragma unroll
            for (int n = 0; n < 4; ++n)
                acc[m][n] = MFMA16x32(af[m], bfr[n], acc[m][n]);
        __syncthreads();
    }

    if (!isQ && col0 >= 1024) {
        // pure-V block: wave-local LDS transpose, coalesced Vt store
        bf16_t* sT = (bf16_t*)(pool + 16384) + w * (64 * 72);
        const int j0  = col0 - 1024 + wc * 64;
        const int hh  = j0 >> 6;
        const int sk0 = row0 + wr * 64;
        const int bb  = sk0 >> 11;
        const int skl = sk0 & 2047;
#pragma unroll
        for (int n = 0; n < 4; ++n) {
            int hd = n * 16 + l15;
            float bv = bkv[1024 + j0 + n * 16 + l15];
#pragma unroll
            for (int m = 0; m < 4; ++m) {
                bf16x4 v4;
                v4[0] = (bf16_t)(acc[m][n][0] + bv);
                v4[1] = (bf16_t)(acc[m][n][1] + bv);
                v4[2] = (bf16_t)(acc[m][n][2] + bv);
                v4[3] = (bf16_t)(acc[m][n][3] + bv);
                *(bf16x4*)(sT + hd * 72 + m * 16 + quad * 4) = v4;
            }
        }
        bf16_t* vdst = Vt + (((size_t)(bb * 16 + hh) * 64) << 11) + skl;
#pragma unroll
        for (int it = 0; it < 8; ++it) {
            int hd = it * 8 + (lane >> 3);
            int sc = (lane & 7) * 8;
            bf16x8 v = *(const bf16x8*)(sT + hd * 72 + sc);
            *(bf16x8*)(vdst + ((size_t)hd << 11) + sc) = v;
        }
        return;
    }

#pragma unroll
    for (int m = 0; m < 4; ++m) {
        int rg_base = row0 + wr * 64 + m * 16 + quad * 4;
#pragma unroll
        for (int n = 0; n < 4; ++n) {
            int cg = col0 + wc * 64 + n * 16 + l15;
            float bv = bias[cg];
#pragma unroll
            for (int r = 0; r < 4; ++r) {
                int rg = rg_base + r;
                float v = acc[m][n][r] + bv;
                int bb = rg >> 11, sr = rg & 2047;
                int hh = cg >> 6, hd = cg & 63;
                size_t idx = (((size_t)(bb * 16 + hh) * 2048 + sr) << 6) | hd;
                if (isQ) Qp[idx] = (bf16_t)(v * ATTN_SCALE);
                else     Kb[idx] = (bf16_t)v;
            }
        }
    }
}

// ---------------------------------------------------------------------------
// Oproj GEMM: C = A(MxK) * BT(NxK)^T + bias, fp32 row-major out.
__global__ __launch_bounds__(256, 3)
void gemm_out(const bf16_t* __restrict__ A, const bf16_t* __restrict__ BT,
              const float* __restrict__ bias, float* __restrict__ out,
              int M, int N, int K) {
    __shared__ __align__(16) bf16_t sA[128 * 32];
    __shared__ __align__(16) bf16_t sB[128 * 32];
    const int tid  = threadIdx.x;
    const int lane = tid & 63, w = tid >> 6;
    const int wr = w >> 1, wc = w & 1;
    const int quad = lane >> 4, l15 = lane & 15;
    const int x3 = l15 & 3;
    const int row0 = blockIdx.y * 128, col0 = blockIdx.x * 128;

    f32x4 acc[4][4];
    const f32x4 fz = {0.f, 0.f, 0.f, 0.f};
#pragma unroll
    for (int m = 0; m < 4; ++m)
#pragma unroll
        for (int n = 0; n < 4; ++n) acc[m][n] = fz;

    for (int kt = 0; kt < K; kt += 32) {
#pragma unroll
        for (int i = 0; i < 2; ++i) {
            int c = i * 256 + tid;
            int r = c >> 2, cr = c & 3;
            int g = cr ^ (r & 3);
            gload16(A + (size_t)(row0 + r) * K + kt + g * 8,
                    (const char*)sA + i * 4096 + w * 1024);
            gload16(BT + (size_t)(col0 + r) * K + kt + g * 8,
                    (const char*)sB + i * 4096 + w * 1024);
        }
        __syncthreads();

        bf16x8 af[4], bfr[4];
#pragma unroll
        for (int m = 0; m < 4; ++m)
            af[m] = *(const bf16x8*)(sA + (wr * 64 + m * 16 + l15) * 32 + (quad ^ x3) * 8);
#pragma unroll
        for (int n = 0; n < 4; ++n)
            bfr[n] = *(const bf16x8*)(sB + (wc * 64 + n * 16 + l15) * 32 + (quad ^ x3) * 8);
#pragma unroll
        for (int m = 0; m < 4; ++m)
#pragma unroll
            for (int n = 0; n < 4; ++n)
                acc[m][n] = MFMA16x32(af[m], bfr[n], acc[m][n]);
        __syncthreads();
    }

#pragma unroll
    for (int m = 0; m < 4; ++m) {
        int rg_base = row0 + wr * 64 + m * 16 + quad * 4;
#pragma unroll
        for (int n = 0; n < 4; ++n) {
            int cg = col0 + wc * 64 + n * 16 + l15;
            float bv = bias[cg];
#pragma unroll
            for (int r = 0; r < 4; ++r)
                out[(size_t)(rg_base + r) * N + cg] = acc[m][n][r] + bv;
        }
    }
}

// ---------------------------------------------------------------------------
// Flash attention. 1-D grid of 2048 blocks, bh-MAJOR: bh = id&63, qt = id>>6.
// Consecutive block IDs -> different bh, so under round-robin ID->XCD
// dispatch all 32 q-tiles of one bh land on ONE XCD: per-XCD KV working set
// = 8 bh x 512 KB = 4 MB = L2 size (was 16 MB -> thrash in R6).
// Wave w owns keys [w*16,w*16+16) of each 64-key tile, all 64 q-rows.
// S^T = K*Q^T so P stays in registers in 16x16x16 A-frag layout; row sums
// accumulate via MFMA against a ones B-fragment.
// LDS tiles: 64 rows x 128B, 16B chunk k of row r stored in slot k^(r&7).
// Pool (36864 B, 4 blocks/CU): sQ@0 (dies after preload; V buf 1 reuses it),
// K bufs @8192/@16384, V bufs @24576/@0; epilogue redO@0 (32K), redL@32768.
__global__ __launch_bounds__(256, 4)
void attn_kernel(const bf16_t* __restrict__ Qp, const bf16_t* __restrict__ Kb,
                 const bf16_t* __restrict__ Vt, bf16_t* __restrict__ Ob) {
    __shared__ __align__(16) char pool[36864];
    bf16_t* sQ   = (bf16_t*)pool;
    float*  redO = (float*)pool;               // [4][64][32] (end phase)
    float*  redL = (float*)(pool + 32768);     // [4][64]

    const int tid = threadIdx.x;
    const int lane = tid & 63, w = tid >> 6;
    const int quad = lane >> 4, l15 = lane & 15;
    const int x7 = l15 & 7;
    const int bhid = blockIdx.x & 63;          // bh fastest -> XCD locality
    const int qt   = blockIdx.x >> 6;
    const int b = bhid >> 4, h = bhid & 15;
    const size_t bh = (size_t)bhid;

    const bf16_t* Qg = Qp + bh * (2048 * 64) + (size_t)qt * (64 * 64);
    const bf16_t* Kg = Kb + bh * (2048 * 64);
    const bf16_t* Vg = Vt + bh * (64 * 2048);

    // staging map: LDS chunk (row, slot) holds global chunk slot^(row&7)
    const int srow = tid >> 3;                 // row 0..31 (+32 for issue 1)
    const int sg   = (tid & 7) ^ (srow & 7);   // global chunk for our slot

    // stage Q + K/V tile 0
#pragma unroll
    for (int hh = 0; hh < 2; ++hh) {
        int row = hh * 32 + srow;
        gload16(Qg + (size_t)row * 64 + sg * 8, pool + hh * 4096 + w * 1024);
        gload16(Kg + (size_t)row * 64 + sg * 8, pool + 8192 + hh * 4096 + w * 1024);
        gload16(Vg + (size_t)row * 2048 + sg * 8, pool + 24576 + hh * 4096 + w * 1024);
    }
    __syncthreads();

    // Q B-frags: all 64 q-rows, both hd halves
    bf16x8 qf[4][2];
#pragma unroll
    for (int qb = 0; qb < 4; ++qb)
#pragma unroll
        for (int hh = 0; hh < 2; ++hh)
            qf[qb][hh] = *(const bf16x8*)(sQ + (qb * 16 + l15) * 64 +
                                          ((hh * 4 + quad) ^ x7) * 8);
    // retire the qf ds_reads in every wave BEFORE V buf 1 (same LDS) is staged
    __syncthreads();

    const f32x4 fz = {0.f, 0.f, 0.f, 0.f};
    const bf16x4 ones = {(bf16_t)1.f, (bf16_t)1.f, (bf16_t)1.f, (bf16_t)1.f};
    f32x4 o_[4][4];   // [qb][nh]: O[qb*16+quad*4+r][nh*16+l15], partial over our keys
    f32x4 lacc[4];    // [qb]: row-sum partials
#pragma unroll
    for (int qb = 0; qb < 4; ++qb) {
        lacc[qb] = fz;
#pragma unroll
        for (int nh = 0; nh < 4; ++nh) o_[qb][nh] = fz;
    }

    for (int t = 0; t < 32; ++t) {
        if (t < 31) {
            const bf16_t* Kt = Kg + (size_t)(t + 1) * (64 * 64);
            char* kb_ = pool + 8192 + (((t + 1) & 1) << 13);
            char* vb_ = ((t + 1) & 1) ? pool : pool + 24576;
#pragma unroll
            for (int hh = 0; hh < 2; ++hh) {
                int row = hh * 32 + srow;
                gload16(Kt + (size_t)row * 64 + sg * 8, kb_ + hh * 4096 + w * 1024);
                gload16(Vg + (size_t)row * 2048 + (t + 1) * 64 + sg * 8,
                        vb_ + hh * 4096 + w * 1024);
            }
        }
        const bf16_t* k0 = (const bf16_t*)(pool + 8192 + ((t & 1) << 13));
        const bf16_t* v0 = (const bf16_t*)((t & 1) ? pool : pool + 24576);

        // K A-frags for our 16 keys
        const bf16_t* krow = k0 + (w * 16 + l15) * 64;
        bf16x8 kf0 = *(const bf16x8*)(krow + (quad ^ x7) * 8);
        bf16x8 kf1 = *(const bf16x8*)(krow + ((quad + 4) ^ x7) * 8);

        // S^T[key=w*16+quad*4+r][qrow=qb*16+l15]
        f32x4 s[4];
#pragma unroll
        for (int qb = 0; qb < 4; ++qb) {
            s[qb] = MFMA16x32(kf0, qf[qb][0], fz);
            s[qb] = MFMA16x32(kf1, qf[qb][1], s[qb]);
        }

        // p = exp2(s); row sums via MFMA(p, ones)
        bf16x4 pf[4];
#pragma unroll
        for (int qb = 0; qb < 4; ++qb) {
            bf16x4 pv;
            pv[0] = (bf16_t)fast_exp2(s[qb][0]);
            pv[1] = (bf16_t)fast_exp2(s[qb][1]);
            pv[2] = (bf16_t)fast_exp2(s[qb][2]);
            pv[3] = (bf16_t)fast_exp2(s[qb][3]);
            pf[qb] = pv;
            lacc[qb] = mfma16x16(pf[qb], ones, lacc[qb]);
        }

        // V B-frags: V[key=w*16+quad*4+j][hd=nh*16+l15] from swizzled V^T tile
        const int vslot = (2 * w + (quad >> 1)) ^ x7;
        const int vsub  = (quad & 1) * 4;
#pragma unroll
        for (int nh = 0; nh < 4; ++nh) {
            bf16x4 vf = *(const bf16x4*)(v0 + (nh * 16 + l15) * 64 + vslot * 8 + vsub);
#pragma unroll
            for (int qb = 0; qb < 4; ++qb)
                o_[qb][nh] = mfma16x16(pf[qb], vf, o_[qb][nh]);
        }
        __syncthreads();
    }

    // ---- epilogue ----
    if (l15 == 0) {
#pragma unroll
        for (int qb = 0; qb < 4; ++qb)
#pragma unroll
            for (int r = 0; r < 4; ++r)
                redL[w * 64 + qb * 16 + quad * 4 + r] = lacc[qb][r];
    }

    const int cq = tid >> 2;            // consumer q-row 0..63
    const int chb = (tid & 3) * 8;      // consumer hd base within 32-phase
    const size_t orow = (size_t)b * 2048 + (size_t)qt * 64 + cq;

#pragma unroll
    for (int ph = 0; ph < 2; ++ph) {
        __syncthreads();  // prior phase consumed; redL visible (ph=0)
#pragma unroll
        for (int qb = 0; qb < 4; ++qb)
#pragma unroll
            for (int nj = 0; nj < 2; ++nj) {
                int nh = ph * 2 + nj;
#pragma unroll
                for (int r = 0; r < 4; ++r)
                    redO[w * 2048 + (qb * 16 + quad * 4 + r) * 32 + nj * 16 + l15] =
                        o_[qb][nh][r];
            }
        __syncthreads();  // partials visible

        float lt = redL[cq] + redL[64 + cq] + redL[128 + cq] + redL[192 + cq];
        float linv = 1.f / lt;
        float4 a0 = {0, 0, 0, 0}, a1 = {0, 0, 0, 0};
#pragma unroll
        for (int ww = 0; ww < 4; ++ww) {
            const float4* p = (const float4*)(redO + ww * 2048 + cq * 32 + chb);
            float4 x = p[0], y = p[1];
            a0.x += x.x; a0.y += x.y; a0.z += x.z; a0.w += x.w;
            a1.x += y.x; a1.y += y.y; a1.z += y.z; a1.w += y.w;
        }
        bf16x8 ov;
        ov[0] = (bf16_t)(a0.x * linv); ov[1] = (bf16_t)(a0.y * linv);
        ov[2] = (bf16_t)(a0.z * linv); ov[3] = (bf16_t)(a0.w * linv);
        ov[4] = (bf16_t)(a1.x * linv); ov[5] = (bf16_t)(a1.y * linv);
        ov[6] = (bf16_t)(a1.z * linv); ov[7] = (bf16_t)(a1.w * linv);
        *(bf16x8*)(Ob + orow * 1024 + h * 64 + ph * 32 + chb) = ov;
    }
}

// ---------------------------------------------------------------------------
extern "C" void kernel_launch(void* const* d_in, const int* in_sizes, int n_in,
                              void* d_out, int out_size, void* d_ws, size_t ws_size,
                              hipStream_t stream) {
    const float* query     = (const float*)d_in[0];
    const float* key_value = (const float*)d_in[1];
    const float* Wq  = (const float*)d_in[2];
    const float* bq  = (const float*)d_in[3];
    const float* Wkv = (const float*)d_in[4];
    const float* bkv = (const float*)d_in[5];
    const float* Wo  = (const float*)d_in[6];
    const float* bo  = (const float*)d_in[7];
    float* out = (float*)d_out;

    char* ws = (char*)d_ws;
    const size_t MB = 1024 * 1024;
    bf16_t* WqT  = (bf16_t*)(ws + 0 * MB);
    bf16_t* WkvT = (bf16_t*)(ws + 2 * MB);
    bf16_t* WoT  = (bf16_t*)(ws + 6 * MB);
    bf16_t* qb   = (bf16_t*)(ws + 8 * MB);
    bf16_t* kvb  = (bf16_t*)(ws + 24 * MB);
    bf16_t* Qp   = (bf16_t*)(ws + 40 * MB);
    bf16_t* Kb   = (bf16_t*)(ws + 56 * MB);
    bf16_t* Vt   = (bf16_t*)(ws + 72 * MB);
    bf16_t* Ob   = (bf16_t*)(ws + 88 * MB);

    prep_kernel<<<9728, 256, 0, stream>>>(query, key_value, Wq, Wkv, Wo,
                                          qb, kvb, WqT, WkvT, WoT);
    gemm_qkv<<<dim3(24, 64), 256, 0, stream>>>(qb, kvb, WqT, WkvT, bq, bkv,
                                               Qp, Kb, Vt);
    attn_kernel<<<2048, 256, 0, stream>>>(Qp, Kb, Vt, Ob);
    gemm_out<<<dim3(8, 64), 256, 0, stream>>>(Ob, WoT, bo, out, 8192, 1024, 1024);
}

// Round 8
// 317.334 us; speedup vs baseline: 1.5196x; 1.5196x over previous
//
#include <hip/hip_runtime.h>
#include <hip/hip_bf16.h>
#include <stdint.h>

// ---------------------------------------------------------------------------
// EfficientCrossAttention on MI355X (gfx950), bf16 MFMA pipeline.
// prep (cast+transpose) -> fused Q/KV projection GEMM -> flash attention
// (S^T trick, lsum-via-MFMA, 3 blocks/CU — 4 caused register SPILL in R6/R7:
// ~145 regs needed vs 128 budget at 4 waves/SIMD -> scratch traffic tripled
// FETCH and pinned both pipes at 18%) -> Oproj GEMM.
// d_ws layout:
//   WqT @0MB  WkvT @2MB  WoT @6MB  qb @8MB  kvb @24MB
//   Qp (B*H,2048,64) @40MB   Kb (B*H,2048,64) @56MB
//   Vt (B*H,64,2048) @72MB   Ob (8192x1024)   @88MB
// ---------------------------------------------------------------------------

typedef __bf16 bf16_t;
typedef __bf16 bf16x8 __attribute__((ext_vector_type(8)));
typedef __bf16 bf16x4 __attribute__((ext_vector_type(4)));
typedef short  s16x4  __attribute__((ext_vector_type(4)));
typedef float  f32x4  __attribute__((ext_vector_type(4)));

#define MFMA16x32(a, b, c) __builtin_amdgcn_mfma_f32_16x16x32_bf16((a), (b), (c), 0, 0, 0)

__device__ __forceinline__ f32x4 mfma16x16(bf16x4 a, bf16x4 b, f32x4 c) {
#if __has_builtin(__builtin_amdgcn_mfma_f32_16x16x16_bf16)
    return __builtin_amdgcn_mfma_f32_16x16x16_bf16(a, b, c, 0, 0, 0);
#else
    return __builtin_amdgcn_mfma_f32_16x16x16bf16_1k(
        __builtin_bit_cast(s16x4, a), __builtin_bit_cast(s16x4, b), c, 0, 0, 0);
#endif
}

__device__ __forceinline__ float fast_exp2(float x) {
#if __has_builtin(__builtin_amdgcn_exp2f)
    return __builtin_amdgcn_exp2f(x);
#else
    return exp2f(x);
#endif
}

// async global->LDS, 16B/lane; LDS dest = wave-uniform base + lane*16
__device__ __forceinline__ void gload16(const void* g, const void* l) {
    __builtin_amdgcn_global_load_lds(
        (__attribute__((address_space(1))) void*)(uintptr_t)g,
        (__attribute__((address_space(3))) void*)(uintptr_t)l,
        16, 0, 0);
}

// log2(e)/sqrt(HD=64), folded into the Q projection epilogue
#define ATTN_SCALE 0.18033688011112042f

// ---------------------------------------------------------------------------
// merged prep: fp32->bf16 casts (blocks 0..8191) + 3 weight transposes
__global__ void prep_kernel(const float* __restrict__ q, const float* __restrict__ kv,
                            const float* __restrict__ Wq, const float* __restrict__ Wkv,
                            const float* __restrict__ Wo, bf16_t* __restrict__ qb,
                            bf16_t* __restrict__ kvb, bf16_t* __restrict__ WqT,
                            bf16_t* __restrict__ WkvT, bf16_t* __restrict__ WoT) {
    __shared__ float tile[64][65];
    int bid = blockIdx.x;
    const int t = threadIdx.x;
    if (bid < 8192) {
        const float* in;
        bf16_t* out;
        if (bid < 4096) { in = q; out = qb; }
        else            { in = kv; out = kvb; bid -= 4096; }
        int i = (bid * 256 + t) * 8;
        const float4* p = (const float4*)(in + i);
        float4 x = p[0], y = p[1];
        bf16x8 v;
        v[0] = (bf16_t)x.x; v[1] = (bf16_t)x.y; v[2] = (bf16_t)x.z; v[3] = (bf16_t)x.w;
        v[4] = (bf16_t)y.x; v[5] = (bf16_t)y.y; v[6] = (bf16_t)y.z; v[7] = (bf16_t)y.w;
        *(bf16x8*)(out + i) = v;
        return;
    }
    bid -= 8192;
    int z = bid >> 9, rem = bid & 511;
    int xb = rem & 31, yb = rem >> 5;
    const float* W;
    bf16_t* WT;
    int N;
    if (z == 0)      { W = Wq;  WT = WqT;  N = 1024; }
    else if (z == 1) { W = Wkv; WT = WkvT; N = 2048; }
    else             { W = Wo;  WT = WoT;  N = 1024; }
    if (xb * 64 >= N) return;
    const int K = 1024;
    const int n0 = xb * 64, k0 = yb * 64;
#pragma unroll
    for (int i = 0; i < 16; ++i) {
        int idx = i * 256 + t;
        int r = idx >> 6, c = idx & 63;
        tile[r][c] = W[(size_t)(k0 + r) * N + n0 + c];
    }
    __syncthreads();
#pragma unroll
    for (int i = 0; i < 16; ++i) {
        int idx = i * 256 + t;
        int r = idx >> 6, c = idx & 63;
        WT[(size_t)(n0 + r) * K + k0 + c] = (bf16_t)tile[c][r];
    }
}

// ---------------------------------------------------------------------------
// Fused Q + KV projection GEMM (one launch, 24x64 = 1536 blocks).
// blockIdx.x < 8: Qproj (scaled, -> Qp); else KVproj (-> Kb / Vt).
// 128x128 tiles, m97 staging, 2-bit XOR chunk swizzle.
__global__ __launch_bounds__(256, 3)
void gemm_qkv(const bf16_t* __restrict__ qb, const bf16_t* __restrict__ kvb,
              const bf16_t* __restrict__ WqT, const bf16_t* __restrict__ WkvT,
              const float* __restrict__ bq, const float* __restrict__ bkv,
              bf16_t* __restrict__ Qp, bf16_t* __restrict__ Kb,
              bf16_t* __restrict__ Vt) {
    __shared__ __align__(16) char pool[16384 + 4 * 64 * 72 * 2];
    bf16_t* sA = (bf16_t*)pool;
    bf16_t* sB = (bf16_t*)(pool + 8192);

    const int tid  = threadIdx.x;
    const int lane = tid & 63, w = tid >> 6;
    const int wr = w >> 1, wc = w & 1;
    const int quad = lane >> 4, l15 = lane & 15;
    const int x3 = l15 & 3;
    const bool isQ = blockIdx.x < 8;
    const bf16_t* A    = isQ ? qb : kvb;
    const bf16_t* BT   = isQ ? WqT : WkvT;
    const float*  bias = isQ ? bq : bkv;
    const int row0 = blockIdx.y * 128;
    const int col0 = (isQ ? blockIdx.x : (blockIdx.x - 8)) * 128;
    const int K = 1024;

    f32x4 acc[4][4];
    const f32x4 fz = {0.f, 0.f, 0.f, 0.f};
#pragma unroll
    for (int m = 0; m < 4; ++m)
#pragma unroll
        for (int n = 0; n < 4; ++n) acc[m][n] = fz;

    for (int kt = 0; kt < K; kt += 32) {
#pragma unroll
        for (int i = 0; i < 2; ++i) {
            int c = i * 256 + tid;
            int r = c >> 2, cr = c & 3;
            int g = cr ^ (r & 3);
            gload16(A + (size_t)(row0 + r) * K + kt + g * 8,
                    (const char*)sA + i * 4096 + w * 1024);
            gload16(BT + (size_t)(col0 + r) * K + kt + g * 8,
                    (const char*)sB + i * 4096 + w * 1024);
        }
        __syncthreads();

        bf16x8 af[4], bfr[4];
#pragma unroll
        for (int m = 0; m < 4; ++m)
            af[m] = *(const bf16x8*)(sA + (wr * 64 + m * 16 + l15) * 32 + (quad ^ x3) * 8);
#pragma unroll
        for (int n = 0; n < 4; ++n)
            bfr[n] = *(const bf16x8*)(sB + (wc * 64 + n * 16 + l15) * 32 + (quad ^ x3) * 8);
#pragma unroll
        for (int m = 0; m < 4; ++m)
#pragma unroll
            for (int n = 0; n < 4; ++n)
                acc[m][n] = MFMA16x32(af[m], bfr[n], acc[m][n]);
        __syncthreads();
    }

    if (!isQ && col0 >= 1024) {
        // pure-V block: wave-local LDS transpose, coalesced Vt store
        bf16_t* sT = (bf16_t*)(pool + 16384) + w * (64 * 72);
        const int j0  = col0 - 1024 + wc * 64;
        const int hh  = j0 >> 6;
        const int sk0 = row0 + wr * 64;
        const int bb  = sk0 >> 11;
        const int skl = sk0 & 2047;
#pragma unroll
        for (int n = 0; n < 4; ++n) {
            int hd = n * 16 + l15;
            float bv = bkv[1024 + j0 + n * 16 + l15];
#pragma unroll
            for (int m = 0; m < 4; ++m) {
                bf16x4 v4;
                v4[0] = (bf16_t)(acc[m][n][0] + bv);
                v4[1] = (bf16_t)(acc[m][n][1] + bv);
                v4[2] = (bf16_t)(acc[m][n][2] + bv);
                v4[3] = (bf16_t)(acc[m][n][3] + bv);
                *(bf16x4*)(sT + hd * 72 + m * 16 + quad * 4) = v4;
            }
        }
        bf16_t* vdst = Vt + (((size_t)(bb * 16 + hh) * 64) << 11) + skl;
#pragma unroll
        for (int it = 0; it < 8; ++it) {
            int hd = it * 8 + (lane >> 3);
            int sc = (lane & 7) * 8;
            bf16x8 v = *(const bf16x8*)(sT + hd * 72 + sc);
            *(bf16x8*)(vdst + ((size_t)hd << 11) + sc) = v;
        }
        return;
    }

#pragma unroll
    for (int m = 0; m < 4; ++m) {
        int rg_base = row0 + wr * 64 + m * 16 + quad * 4;
#pragma unroll
        for (int n = 0; n < 4; ++n) {
            int cg = col0 + wc * 64 + n * 16 + l15;
            float bv = bias[cg];
#pragma unroll
            for (int r = 0; r < 4; ++r) {
                int rg = rg_base + r;
                float v = acc[m][n][r] + bv;
                int bb = rg >> 11, sr = rg & 2047;
                int hh = cg >> 6, hd = cg & 63;
                size_t idx = (((size_t)(bb * 16 + hh) * 2048 + sr) << 6) | hd;
                if (isQ) Qp[idx] = (bf16_t)(v * ATTN_SCALE);
                else     Kb[idx] = (bf16_t)v;
            }
        }
    }
}

// ---------------------------------------------------------------------------
// Oproj GEMM: C = A(MxK) * BT(NxK)^T + bias, fp32 row-major out.
__global__ __launch_bounds__(256, 3)
void gemm_out(const bf16_t* __restrict__ A, const bf16_t* __restrict__ BT,
              const float* __restrict__ bias, float* __restrict__ out,
              int M, int N, int K) {
    __shared__ __align__(16) bf16_t sA[128 * 32];
    __shared__ __align__(16) bf16_t sB[128 * 32];
    const int tid  = threadIdx.x;
    const int lane = tid & 63, w = tid >> 6;
    const int wr = w >> 1, wc = w & 1;
    const int quad = lane >> 4, l15 = lane & 15;
    const int x3 = l15 & 3;
    const int row0 = blockIdx.y * 128, col0 = blockIdx.x * 128;

    f32x4 acc[4][4];
    const f32x4 fz = {0.f, 0.f, 0.f, 0.f};
#pragma unroll
    for (int m = 0; m < 4; ++m)
#pragma unroll
        for (int n = 0; n < 4; ++n) acc[m][n] = fz;

    for (int kt = 0; kt < K; kt += 32) {
#pragma unroll
        for (int i = 0; i < 2; ++i) {
            int c = i * 256 + tid;
            int r = c >> 2, cr = c & 3;
            int g = cr ^ (r & 3);
            gload16(A + (size_t)(row0 + r) * K + kt + g * 8,
                    (const char*)sA + i * 4096 + w * 1024);
            gload16(BT + (size_t)(col0 + r) * K + kt + g * 8,
                    (const char*)sB + i * 4096 + w * 1024);
        }
        __syncthreads();

        bf16x8 af[4], bfr[4];
#pragma unroll
        for (int m = 0; m < 4; ++m)
            af[m] = *(const bf16x8*)(sA + (wr * 64 + m * 16 + l15) * 32 + (quad ^ x3) * 8);
#pragma unroll
        for (int n = 0; n < 4; ++n)
            bfr[n] = *(const bf16x8*)(sB + (wc * 64 + n * 16 + l15) * 32 + (quad ^ x3) * 8);
#pragma unroll
        for (int m = 0; m < 4; ++m)
#pragma unroll
            for (int n = 0; n < 4; ++n)
                acc[m][n] = MFMA16x32(af[m], bfr[n], acc[m][n]);
        __syncthreads();
    }

#pragma unroll
    for (int m = 0; m < 4; ++m) {
        int rg_base = row0 + wr * 64 + m * 16 + quad * 4;
#pragma unroll
        for (int n = 0; n < 4; ++n) {
            int cg = col0 + wc * 64 + n * 16 + l15;
            float bv = bias[cg];
#pragma unroll
            for (int r = 0; r < 4; ++r)
                out[(size_t)(rg_base + r) * N + cg] = acc[m][n][r] + bv;
        }
    }
}

// ---------------------------------------------------------------------------
// Flash attention. 1-D grid of 2048 blocks, bh-major: bh = id&63, qt = id>>6.
// Wave w owns keys [w*16,w*16+16) of each 64-key tile, all 64 q-rows.
// S^T = K*Q^T so P stays in registers in 16x16x16 A-frag layout; row sums
// accumulate via MFMA against a ones B-fragment.
// LDS tiles: 64 rows x 128B, 16B chunk k of row r stored in slot k^(r&7).
// Pool (36864 B): sQ@0 (dies after preload; V buf 1 reuses it),
// K bufs @8192/@16384, V bufs @24576/@0; epilogue redO@0 (32K), redL@32768.
// __launch_bounds__(256,3): ~170-reg budget fits the ~145-reg live set.
// (256,4) = 128-reg budget SPILLS (R6/R7: FETCH 3x, both pipes 18%).
__global__ __launch_bounds__(256, 3)
void attn_kernel(const bf16_t* __restrict__ Qp, const bf16_t* __restrict__ Kb,
                 const bf16_t* __restrict__ Vt, bf16_t* __restrict__ Ob) {
    __shared__ __align__(16) char pool[36864];
    bf16_t* sQ   = (bf16_t*)pool;
    float*  redO = (float*)pool;               // [4][64][32] (end phase)
    float*  redL = (float*)(pool + 32768);     // [4][64]

    const int tid = threadIdx.x;
    const int lane = tid & 63, w = tid >> 6;
    const int quad = lane >> 4, l15 = lane & 15;
    const int x7 = l15 & 7;
    const int bhid = blockIdx.x & 63;
    const int qt   = blockIdx.x >> 6;
    const int b = bhid >> 4, h = bhid & 15;
    const size_t bh = (size_t)bhid;

    const bf16_t* Qg = Qp + bh * (2048 * 64) + (size_t)qt * (64 * 64);
    const bf16_t* Kg = Kb + bh * (2048 * 64);
    const bf16_t* Vg = Vt + bh * (64 * 2048);

    // staging map: LDS chunk (row, slot) holds global chunk slot^(row&7)
    const int srow = tid >> 3;                 // row 0..31 (+32 for issue 1)
    const int sg   = (tid & 7) ^ (srow & 7);   // global chunk for our slot

    // stage Q + K/V tile 0
#pragma unroll
    for (int hh = 0; hh < 2; ++hh) {
        int row = hh * 32 + srow;
        gload16(Qg + (size_t)row * 64 + sg * 8, pool + hh * 4096 + w * 1024);
        gload16(Kg + (size_t)row * 64 + sg * 8, pool + 8192 + hh * 4096 + w * 1024);
        gload16(Vg + (size_t)row * 2048 + sg * 8, pool + 24576 + hh * 4096 + w * 1024);
    }
    __syncthreads();

    // Q B-frags: all 64 q-rows, both hd halves
    bf16x8 qf[4][2];
#pragma unroll
    for (int qb = 0; qb < 4; ++qb)
#pragma unroll
        for (int hh = 0; hh < 2; ++hh)
            qf[qb][hh] = *(const bf16x8*)(sQ + (qb * 16 + l15) * 64 +
                                          ((hh * 4 + quad) ^ x7) * 8);
    // retire the qf ds_reads in every wave BEFORE V buf 1 (same LDS) is staged
    __syncthreads();

    const f32x4 fz = {0.f, 0.f, 0.f, 0.f};
    const bf16x4 ones = {(bf16_t)1.f, (bf16_t)1.f, (bf16_t)1.f, (bf16_t)1.f};
    f32x4 o_[4][4];   // [qb][nh]: O[qb*16+quad*4+r][nh*16+l15], partial over our keys
    f32x4 lacc[4];    // [qb]: row-sum partials
#pragma unroll
    for (int qb = 0; qb < 4; ++qb) {
        lacc[qb] = fz;
#pragma unroll
        for (int nh = 0; nh < 4; ++nh) o_[qb][nh] = fz;
    }

    for (int t = 0; t < 32; ++t) {
        if (t < 31) {
            const bf16_t* Kt = Kg + (size_t)(t + 1) * (64 * 64);
            char* kb_ = pool + 8192 + (((t + 1) & 1) << 13);
            char* vb_ = ((t + 1) & 1) ? pool : pool + 24576;
#pragma unroll
            for (int hh = 0; hh < 2; ++hh) {
                int row = hh * 32 + srow;
                gload16(Kt + (size_t)row * 64 + sg * 8, kb_ + hh * 4096 + w * 1024);
                gload16(Vg + (size_t)row * 2048 + (t + 1) * 64 + sg * 8,
                        vb_ + hh * 4096 + w * 1024);
            }
        }
        const bf16_t* k0 = (const bf16_t*)(pool + 8192 + ((t & 1) << 13));
        const bf16_t* v0 = (const bf16_t*)((t & 1) ? pool : pool + 24576);

        // K A-frags for our 16 keys
        const bf16_t* krow = k0 + (w * 16 + l15) * 64;
        bf16x8 kf0 = *(const bf16x8*)(krow + (quad ^ x7) * 8);
        bf16x8 kf1 = *(const bf16x8*)(krow + ((quad + 4) ^ x7) * 8);

        // S^T[key=w*16+quad*4+r][qrow=qb*16+l15]
        f32x4 s[4];
#pragma unroll
        for (int qb = 0; qb < 4; ++qb) {
            s[qb] = MFMA16x32(kf0, qf[qb][0], fz);
            s[qb] = MFMA16x32(kf1, qf[qb][1], s[qb]);
        }

        // p = exp2(s); row sums via MFMA(p, ones)
        bf16x4 pf[4];
#pragma unroll
        for (int qb = 0; qb < 4; ++qb) {
            bf16x4 pv;
            pv[0] = (bf16_t)fast_exp2(s[qb][0]);
            pv[1] = (bf16_t)fast_exp2(s[qb][1]);
            pv[2] = (bf16_t)fast_exp2(s[qb][2]);
            pv[3] = (bf16_t)fast_exp2(s[qb][3]);
            pf[qb] = pv;
            lacc[qb] = mfma16x16(pf[qb], ones, lacc[qb]);
        }

        // V B-frags: V[key=w*16+quad*4+j][hd=nh*16+l15] from swizzled V^T tile
        const int vslot = (2 * w + (quad >> 1)) ^ x7;
        const int vsub  = (quad & 1) * 4;
#pragma unroll
        for (int nh = 0; nh < 4; ++nh) {
            bf16x4 vf = *(const bf16x4*)(v0 + (nh * 16 + l15) * 64 + vslot * 8 + vsub);
#pragma unroll
            for (int qb = 0; qb < 4; ++qb)
                o_[qb][nh] = mfma16x16(pf[qb], vf, o_[qb][nh]);
        }
        __syncthreads();
    }

    // ---- epilogue ----
    if (l15 == 0) {
#pragma unroll
        for (int qb = 0; qb < 4; ++qb)
#pragma unroll
            for (int r = 0; r < 4; ++r)
                redL[w * 64 + qb * 16 + quad * 4 + r] = lacc[qb][r];
    }

    const int cq = tid >> 2;            // consumer q-row 0..63
    const int chb = (tid & 3) * 8;      // consumer hd base within 32-phase
    const size_t orow = (size_t)b * 2048 + (size_t)qt * 64 + cq;

#pragma unroll
    for (int ph = 0; ph < 2; ++ph) {
        __syncthreads();  // prior phase consumed; redL visible (ph=0)
#pragma unroll
        for (int qb = 0; qb < 4; ++qb)
#pragma unroll
            for (int nj = 0; nj < 2; ++nj) {
                int nh = ph * 2 + nj;
#pragma unroll
                for (int r = 0; r < 4; ++r)
                    redO[w * 2048 + (qb * 16 + quad * 4 + r) * 32 + nj * 16 + l15] =
                        o_[qb][nh][r];
            }
        __syncthreads();  // partials visible

        float lt = redL[cq] + redL[64 + cq] + redL[128 + cq] + redL[192 + cq];
        float linv = 1.f / lt;
        float4 a0 = {0, 0, 0, 0}, a1 = {0, 0, 0, 0};
#pragma unroll
        for (int ww = 0; ww < 4; ++ww) {
            const float4* p = (const float4*)(redO + ww * 2048 + cq * 32 + chb);
            float4 x = p[0], y = p[1];
            a0.x += x.x; a0.y += x.y; a0.z += x.z; a0.w += x.w;
            a1.x += y.x; a1.y += y.y; a1.z += y.z; a1.w += y.w;
        }
        bf16x8 ov;
        ov[0] = (bf16_t)(a0.x * linv); ov[1] = (bf16_t)(a0.y * linv);
        ov[2] = (bf16_t)(a0.z * linv); ov[3] = (bf16_t)(a0.w * linv);
        ov[4] = (bf16_t)(a1.x * linv); ov[5] = (bf16_t)(a1.y * linv);
        ov[6] = (bf16_t)(a1.z * linv); ov[7] = (bf16_t)(a1.w * linv);
        *(bf16x8*)(Ob + orow * 1024 + h * 64 + ph * 32 + chb) = ov;
    }
}

// ---------------------------------------------------------------------------
extern "C" void kernel_launch(void* const* d_in, const int* in_sizes, int n_in,
                              void* d_out, int out_size, void* d_ws, size_t ws_size,
                              hipStream_t stream) {
    const float* query     = (const float*)d_in[0];
    const float* key_value = (const float*)d_in[1];
    const float* Wq  = (const float*)d_in[2];
    const float* bq  = (const float*)d_in[3];
    const float* Wkv = (const float*)d_in[4];
    const float* bkv = (const float*)d_in[5];
    const float* Wo  = (const float*)d_in[6];
    const float* bo  = (const float*)d_in[7];
    float* out = (float*)d_out;

    char* ws = (char*)d_ws;
    const size_t MB = 1024 * 1024;
    bf16_t* WqT  = (bf16_t*)(ws + 0 * MB);
    bf16_t* WkvT = (bf16_t*)(ws + 2 * MB);
    bf16_t* WoT  = (bf16_t*)(ws + 6 * MB);
    bf16_t* qb   = (bf16_t*)(ws + 8 * MB);
    bf16_t* kvb  = (bf16_t*)(ws + 24 * MB);
    bf16_t* Qp   = (bf16_t*)(ws + 40 * MB);
    bf16_t* Kb   = (bf16_t*)(ws + 56 * MB);
    bf16_t* Vt   = (bf16_t*)(ws + 72 * MB);
    bf16_t* Ob   = (bf16_t*)(ws + 88 * MB);

    prep_kernel<<<9728, 256, 0, stream>>>(query, key_value, Wq, Wkv, Wo,
                                          qb, kvb, WqT, WkvT, WoT);
    gemm_qkv<<<dim3(24, 64), 256, 0, stream>>>(qb, kvb, WqT, WkvT, bq, bkv,
                                               Qp, Kb, Vt);
    attn_kernel<<<2048, 256, 0, stream>>>(Qp, Kb, Vt, Ob);
    gemm_out<<<dim3(8, 64), 256, 0, stream>>>(Ob, WoT, bo, out, 8192, 1024, 1024);
}